// Round 20
// baseline (220.561 us; speedup 1.0000x reference)
//
#include <hip/hip_runtime.h>
#include <hip/hip_bf16.h>
#include <hip/hip_fp16.h>

// SASA local self-attention, fused. Round 20: R=2 pixel-pair x quarter-channel.
//  - thread = (pair of adjacent queries, 8 channels): window-union reads
//    56 instead of 2x49 -> 1.75x LDS byte cut (K and V)
//  - cross-channel logit reduce via 2 DPP quad_perms (lane^1, lane^2), VALU pipe
//  - online softmax (r12 numerics), ~60 VGPR live set
//  - projection/staging identical to r16; occupancy unchanged (76.6KB, 16 waves/CU)
// B=4, CIN=COUT=256, H=W=64, G=8, CG=32, K=7, PAD=3.
#define TS   16
#define HS   22
#define HP   484
#define KDW  18          // u32 stride per halo pixel (72B, 8B-aligned)
#define KK   7

typedef _Float16 h2 __attribute__((ext_vector_type(2)));
union U32H { unsigned u; h2 h; __half2 p; };

__device__ __forceinline__ h2 pkrtz(float a, float b) {
    auto r = __builtin_amdgcn_cvt_pkrtz(a, b);
    union { decltype(r) i; h2 o; } c; c.i = r;
    return c.o;
}
__device__ __forceinline__ float dot2(h2 a, h2 b, float c) {
#if __has_builtin(__builtin_amdgcn_fdot2)
    return __builtin_amdgcn_fdot2(a, b, c, false);
#else
    return fmaf((float)a.x, (float)b.x, fmaf((float)a.y, (float)b.y, c));
#endif
}
__device__ __forceinline__ float dot2u(unsigned wu, h2 b, float c) {
    U32H w; w.u = wu; return dot2(w.h, b, c);
}
// lane^1 within quad (quad_perm [1,0,3,2])
__device__ __forceinline__ float qswap1(float v) {
#if __has_builtin(__builtin_amdgcn_mov_dpp)
    return __int_as_float(__builtin_amdgcn_mov_dpp(__float_as_int(v), 0xB1, 0xF, 0xF, true));
#else
    return __shfl_xor(v, 1, 64);
#endif
}
// lane^2 within quad (quad_perm [2,3,0,1])
__device__ __forceinline__ float qswap2(float v) {
#if __has_builtin(__builtin_amdgcn_mov_dpp)
    return __int_as_float(__builtin_amdgcn_mov_dpp(__float_as_int(v), 0x4E, 0xF, 0xF, true));
#else
    return __shfl_xor(v, 2, 64);
#endif
}

__global__ __attribute__((amdgpu_flat_work_group_size(512, 512), amdgpu_waves_per_eu(4, 4)))
void sasa_fused_kernel(const float* __restrict__ x,
                       const float* __restrict__ wq,
                       const float* __restrict__ wk,
                       const float* __restrict__ wv,
                       const float* __restrict__ row_emb,
                       const float* __restrict__ col_emb,
                       float* __restrict__ out)
{
    __shared__ h2       s_w[1536];         // [m(k,v,q)*2+hh][cp][co], 6 KB
    __shared__ float    s_emb[224];        // E[c][t], 0.9 KB
    __shared__ unsigned s_ku[HP * KDW];    // K halo, f16 pairs, 34.8 KB
    __shared__ unsigned s_vu[HP * KDW];    // V halo, f16 pairs, 34.8 KB

    const int tid = threadIdx.x;

    // ---- XCD-bijective swizzle (r15) ----
    const int lin  = blockIdx.x + (blockIdx.y << 2) + (blockIdx.z << 4);
    const int xcd  = lin & 7;
    const int slot = lin >> 3;
    const int zg   = xcd + ((slot >> 4) << 3);
    const int sp   = slot & 15;
    const int b    = zg >> 3;
    const int g    = zg & 7;
    const int y0   = (sp >> 2) * TS;
    const int x0   = (sp & 3) * TS;

    const float* xg = x + (size_t)(b * 256 + g * 32) * 4096;

    // ---- pre-issue projection x loads (both items; identical to r16) ----
    const int hh0 = (tid >= HP) ? 1 : 0;
    const int hp0 = tid - (hh0 ? HP : 0);
    const int hy0 = hp0 / HS, hx0 = hp0 - hy0 * HS;
    const int gy0 = y0 + hy0 - 3, gx0 = x0 + hx0 - 3;
    const bool ok0 = ((unsigned)gy0 < 64u) && ((unsigned)gx0 < 64u);

    const int hp1 = tid + 28;
    const int hy1 = hp1 / HS, hx1 = hp1 - hy1 * HS;
    const int gy1 = y0 + hy1 - 3, gx1 = x0 + hx1 - 3;
    const bool it1v = (tid < 2 * HP - 512);
    const bool ok1 = it1v && ((unsigned)gy1 < 64u) && ((unsigned)gx1 < 64u);

    float xr0[32], xr1[32];
    #pragma unroll
    for (int ci = 0; ci < 32; ++ci) { xr0[ci] = 0.f; xr1[ci] = 0.f; }
    if (ok0) {
        const float* xp = xg + gy0 * 64 + gx0;
        #pragma unroll
        for (int ci = 0; ci < 32; ++ci) xr0[ci] = xp[ci * 4096];
    }
    if (ok1) {
        const float* xp = xg + gy1 * 64 + gx1;
        #pragma unroll
        for (int ci = 0; ci < 32; ++ci) xr1[ci] = xp[ci * 4096];
    }

    // ---- stage weights (f16) + emb (f32) ----
    {
        const int cp  = tid & 15;
        const int cog = tid >> 4;
        const int hh  = cog >> 4;
        const int co  = cog & 15;
        const int di  = (hh * 16 + cp) * 16 + co;
        const float2* wk2 = (const float2*)(wk + g * 1024);
        const float2* wv2 = (const float2*)(wv + g * 1024);
        const float2* wq2 = (const float2*)(wq + g * 1024);
        float2 a = wk2[tid]; s_w[di]        = pkrtz(a.x, a.y);
        float2 v = wv2[tid]; s_w[512 + di]  = pkrtz(v.x, v.y);
        float2 q = wq2[tid]; s_w[1024 + di] = pkrtz(q.x, q.y);
    }
    if (tid < 224) {
        int c = tid / KK, t = tid - c * KK;
        s_emb[tid] = (g < 4) ? row_emb[(g * 32 + c) * KK + t]
                             : col_emb[((g - 4) * 32 + c) * KK + t];
    }
    __syncthreads();

    // ---- projection item0 (identical to r16) ----
    {
        h2 xv2[16];
        #pragma unroll
        for (int cp = 0; cp < 16; ++cp) xv2[cp] = pkrtz(xr0[2 * cp], xr0[2 * cp + 1]);
        float accK[16], accV[16];
        #pragma unroll
        for (int c = 0; c < 16; ++c) { accK[c] = 0.f; accV[c] = 0.f; }
        const h2* wkp = s_w + hh0 * 256;
        const h2* wvp = s_w + 512 + hh0 * 256;
        #pragma unroll
        for (int cp = 0; cp < 16; ++cp) {
            h2 xv = xv2[cp];
            const uint4* wkr = (const uint4*)(wkp + cp * 16);
            const uint4* wvr = (const uint4*)(wvp + cp * 16);
            uint4 kw[4] = { wkr[0], wkr[1], wkr[2], wkr[3] };
            uint4 vw[4] = { wvr[0], wvr[1], wvr[2], wvr[3] };
            const unsigned* kwu = (const unsigned*)kw;
            const unsigned* vwu = (const unsigned*)vw;
            #pragma unroll
            for (int co = 0; co < 16; ++co) {
                accK[co] = dot2u(kwu[co], xv, accK[co]);
                accV[co] = dot2u(vwu[co], xv, accV[co]);
            }
        }
        unsigned* dk = s_ku + hp0 * KDW + hh0 * 8;
        unsigned* dv = s_vu + hp0 * KDW + hh0 * 8;
        #pragma unroll
        for (int j = 0; j < 4; ++j) {
            U32H a0, a1, b0, b1;
            a0.h = pkrtz(accK[4 * j],     accK[4 * j + 1]);
            a1.h = pkrtz(accK[4 * j + 2], accK[4 * j + 3]);
            b0.h = pkrtz(accV[4 * j],     accV[4 * j + 1]);
            b1.h = pkrtz(accV[4 * j + 2], accV[4 * j + 3]);
            ((uint2*)dk)[j] = make_uint2(a0.u, a1.u);
            ((uint2*)dv)[j] = make_uint2(b0.u, b1.u);
        }
    }
    // ---- projection item1 (hh=1; identical to r16) ----
    if (it1v) {
        h2 xv2[16];
        #pragma unroll
        for (int cp = 0; cp < 16; ++cp) xv2[cp] = pkrtz(xr1[2 * cp], xr1[2 * cp + 1]);
        float accK[16], accV[16];
        #pragma unroll
        for (int c = 0; c < 16; ++c) { accK[c] = 0.f; accV[c] = 0.f; }
        const h2* wkp = s_w + 256;
        const h2* wvp = s_w + 512 + 256;
        #pragma unroll
        for (int cp = 0; cp < 16; ++cp) {
            h2 xv = xv2[cp];
            const uint4* wkr = (const uint4*)(wkp + cp * 16);
            const uint4* wvr = (const uint4*)(wvp + cp * 16);
            uint4 kw[4] = { wkr[0], wkr[1], wkr[2], wkr[3] };
            uint4 vw[4] = { wvr[0], wvr[1], wvr[2], wvr[3] };
            const unsigned* kwu = (const unsigned*)kw;
            const unsigned* vwu = (const unsigned*)vw;
            #pragma unroll
            for (int co = 0; co < 16; ++co) {
                accK[co] = dot2u(kwu[co], xv, accK[co]);
                accV[co] = dot2u(vwu[co], xv, accV[co]);
            }
        }
        unsigned* dk = s_ku + hp1 * KDW + 8;
        unsigned* dv = s_vu + hp1 * KDW + 8;
        #pragma unroll
        for (int j = 0; j < 4; ++j) {
            U32H a0, a1, b0, b1;
            a0.h = pkrtz(accK[4 * j],     accK[4 * j + 1]);
            a1.h = pkrtz(accK[4 * j + 2], accK[4 * j + 3]);
            b0.h = pkrtz(accV[4 * j],     accV[4 * j + 1]);
            b1.h = pkrtz(accV[4 * j + 2], accV[4 * j + 3]);
            ((uint2*)dk)[j] = make_uint2(a0.u, a1.u);
            ((uint2*)dv)[j] = make_uint2(b0.u, b1.u);
        }
    }

    // ---- attention mapping: thread = (pair pr, quarter h4) ----
    const int pr = tid >> 2;          // 0..127
    const int h4 = tid & 3;           // 8 channels: [h4*8, h4*8+8)
    const int ty = pr >> 3;           // 0..15
    const int pc = pr & 7;            // pair column
    const int x0l = pc * 2;
    const int yy  = y0 + ty;
    const int xxa = x0 + x0l;         // pixel a; pixel b = xxa+1

    // ---- Q projection for both pixels, 8 channels each ----
    float qa[8], qb[8];
    #pragma unroll
    for (int j = 0; j < 8; ++j) { qa[j] = 0.f; qb[j] = 0.f; }
    {
        const float* xpa = xg + yy * 64 + xxa;
        float xa[32], xb[32];
        #pragma unroll
        for (int ci = 0; ci < 32; ++ci) {
            float2 xv = *(const float2*)(xpa + ci * 4096);
            xa[ci] = xv.x; xb[ci] = xv.y;
        }
        h2 xa2[16], xb2[16];
        #pragma unroll
        for (int cp = 0; cp < 16; ++cp) {
            xa2[cp] = pkrtz(xa[2 * cp], xa[2 * cp + 1]);
            xb2[cp] = pkrtz(xb[2 * cp], xb[2 * cp + 1]);
        }
        // weight rows for co in [h4*8, h4*8+8): hh=h4>>1, co_l base (h4&1)*8
        const h2* wqb = s_w + 1024 + ((h4 >> 1) * 16) * 16 + (h4 & 1) * 8;
        #pragma unroll
        for (int cp = 0; cp < 16; ++cp) {
            const uint4* wr = (const uint4*)(wqb + cp * 16);
            uint4 w0 = wr[0], w1 = wr[1];
            const unsigned* wu0 = (const unsigned*)&w0;
            const unsigned* wu1 = (const unsigned*)&w1;
            h2 va = xa2[cp], vb = xb2[cp];
            #pragma unroll
            for (int j = 0; j < 4; ++j) {
                qa[j]     = dot2u(wu0[j], va, qa[j]);
                qb[j]     = dot2u(wu0[j], vb, qb[j]);
                qa[4 + j] = dot2u(wu1[j], va, qa[4 + j]);
                qb[4 + j] = dot2u(wu1[j], vb, qb[4 + j]);
            }
        }
    }

    // ---- qe[7] per pixel over our 8 channels; quad-reduce to full sum ----
    float qea[KK], qeb[KK];
    #pragma unroll
    for (int t = 0; t < KK; ++t) {
        float aa = 0.f, ab = 0.f;
        #pragma unroll
        for (int j = 0; j < 8; ++j) {
            float e = s_emb[(h4 * 8 + j) * KK + t];
            aa = fmaf(qa[j], e, aa);
            ab = fmaf(qb[j], e, ab);
        }
        qea[t] = aa; qeb[t] = ab;
    }
    #pragma unroll
    for (int t = 0; t < KK; ++t) {
        qea[t] += qswap1(qea[t]); qea[t] += qswap2(qea[t]);
        qeb[t] += qswap1(qeb[t]); qeb[t] += qswap2(qeb[t]);
    }

    // ---- pack q (8 ch -> 4 h2 per pixel) ----
    h2 qa2[4], qb2[4];
    #pragma unroll
    for (int j = 0; j < 4; ++j) {
        qa2[j] = pkrtz(qa[2 * j], qa[2 * j + 1]);
        qb2[j] = pkrtz(qb[2 * j], qb[2 * j + 1]);
    }

    __syncthreads();   // s_ku / s_vu complete

    const int rowsel = (g < 4) ? 1 : 0;

    // ---- online-softmax over the 7x8 window union ----
    float ma = -3.0e38f, da = 0.f, mb = -3.0e38f, db = 0.f;
    __half2 oa[4], ob[4];
    #pragma unroll
    for (int j = 0; j < 4; ++j) { oa[j] = __float2half2_rn(0.f); ob[j] = __float2half2_rn(0.f); }

    const unsigned* kbase = s_ku + h4 * 4;
    const unsigned* vbase = s_vu + h4 * 4;

    #pragma unroll
    for (int ki = 0; ki < KK; ++ki) {
        const int hprow = (ty + ki) * HS + x0l;
        #pragma unroll
        for (int c = 0; c < 8; ++c) {
            const int hp = hprow + c;
            const uint2* kp = (const uint2*)(kbase + hp * KDW);
            const uint2* vp = (const uint2*)(vbase + hp * KDW);
            uint2 k0 = kp[0], k1 = kp[1];
            uint2 v0 = vp[0], v1 = vp[1];

            float pa = 0.f, pb = 0.f;
            pa = dot2u(k0.x, qa2[0], pa);  pb = dot2u(k0.x, qb2[0], pb);
            pa = dot2u(k0.y, qa2[1], pa);  pb = dot2u(k0.y, qb2[1], pb);
            pa = dot2u(k1.x, qa2[2], pa);  pb = dot2u(k1.x, qb2[2], pb);
            pa = dot2u(k1.y, qa2[3], pa);  pb = dot2u(k1.y, qb2[3], pb);
            pa += qswap1(pa); pa += qswap2(pa);
            pb += qswap1(pb); pb += qswap2(pb);

            U32H c0, c1, c2, c3;
            c0.u = v0.x; c1.u = v0.y; c2.u = v1.x; c3.u = v1.y;

            if (c < 7) {   // pixel a: kj = c
                float lg = pa + (rowsel ? qea[ki] : qea[c]);
                float pmx  = fmaxf(ma, lg);
                float corr = __expf(ma - pmx);
                float pe   = __expf(lg - pmx);
                da = fmaf(da, corr, pe);
                ma = pmx;
                __half2 pe2   = __float2half2_rn(pe);
                __half2 corr2 = __float2half2_rn(corr);
                oa[0] = __hfma2(c0.p, pe2, __hmul2(oa[0], corr2));
                oa[1] = __hfma2(c1.p, pe2, __hmul2(oa[1], corr2));
                oa[2] = __hfma2(c2.p, pe2, __hmul2(oa[2], corr2));
                oa[3] = __hfma2(c3.p, pe2, __hmul2(oa[3], corr2));
            }
            if (c > 0) {   // pixel b: kj = c-1
                float lg = pb + (rowsel ? qeb[ki] : qeb[c - 1]);
                float pmx  = fmaxf(mb, lg);
                float corr = __expf(mb - pmx);
                float pe   = __expf(lg - pmx);
                db = fmaf(db, corr, pe);
                mb = pmx;
                __half2 pe2   = __float2half2_rn(pe);
                __half2 corr2 = __float2half2_rn(corr);
                ob[0] = __hfma2(c0.p, pe2, __hmul2(ob[0], corr2));
                ob[1] = __hfma2(c1.p, pe2, __hmul2(ob[1], corr2));
                ob[2] = __hfma2(c2.p, pe2, __hmul2(ob[2], corr2));
                ob[3] = __hfma2(c3.p, pe2, __hmul2(ob[3], corr2));
            }
        }
    }

    // ---- write 2 pixels x 8 channels ----
    const float inva = 1.0f / da;
    const float invb = 1.0f / db;
    float* op = out + (size_t)(b * 256 + g * 32 + h4 * 8) * 4096 + yy * 64 + xxa;
    #pragma unroll
    for (int j = 0; j < 4; ++j) {
        float2 fa = __half22float2(oa[j]);
        float2 fb = __half22float2(ob[j]);
        op[(2 * j) * 4096]         = fa.x * inva;
        op[(2 * j + 1) * 4096]     = fa.y * inva;
        op[(2 * j) * 4096 + 1]     = fb.x * invb;
        op[(2 * j + 1) * 4096 + 1] = fb.y * invb;
    }
}

extern "C" void kernel_launch(void* const* d_in, const int* in_sizes, int n_in,
                              void* d_out, int out_size, void* d_ws, size_t ws_size,
                              hipStream_t stream) {
    const float* x       = (const float*)d_in[0];
    const float* wq      = (const float*)d_in[1];
    const float* wk      = (const float*)d_in[2];
    const float* wv      = (const float*)d_in[3];
    const float* row_emb = (const float*)d_in[4];
    const float* col_emb = (const float*)d_in[5];
    float* out = (float*)d_out;

    dim3 grid(4, 4, 32);   // remapped inside kernel (XCD-bijective swizzle)
    dim3 block(512);
    sasa_fused_kernel<<<grid, block, 0, stream>>>(x, wq, wk, wv, row_emb, col_emb, out);
}